// Round 1
// baseline (222.877 us; speedup 1.0000x reference)
//
#include <hip/hip_runtime.h>

// Bezier2Image: splat 128x160 cubic bezier curves (30 samples each) onto
// 60x60 grids with a narrow gaussian (alpha=2e-4), clamp at 1.0.
//
// Strategy: gaussian is ~3px wide -> truncate splat to an 8x8 pixel window
// per sample (error bound ~2e-4 << 2e-2 threshold). Accumulate per-block in
// LDS, flush with global atomics into ws, finalize with min(.,1).

namespace {
constexpr int   kN = 30;            // samples per curve
constexpr int   kW = 60;            // image side
constexpr int   kL = 160;           // curves per batch
constexpr int   kB = 128;           // batch
constexpr float kInvAlpha = 1.0f / 2e-4f;
constexpr float kRadPix = 3.5f;     // truncation radius in pixels
constexpr int   kKW = 8;            // splat window width (<= 2*kRadPix+1)
constexpr int   kPts = kL * kN;     // 4800 points per batch
constexpr int   kSplit = 8;         // L-chunks per batch
constexpr int   kChunk = kPts / kSplit; // 600
constexpr float kInvW = 1.0f / (float)kW;
}

__device__ __forceinline__ void bezier_point(const float* __restrict__ xb, int p,
                                             float& X, float& Y) {
  int l = p / kN;
  int n = p - l * kN;
  float t0 = (float)n * (1.0f / (float)kN);
  float t  = 2.0f * t0 * t0 * t0 - 3.0f * t0 * t0 + 2.0f * t0;
  float t2 = t * t, t3 = t2 * t;
  float B0 = t3;
  float B1 = 3.0f * (t2 - t3);
  float B2 = 3.0f * (t3 - 2.0f * t2 + t);
  float omt = 1.0f - t;
  float B3 = omt * omt * omt;
  const float4* c = (const float4*)(xb + l * 8);
  float4 c0 = c[0];  // (x0,y0,x1,y1)
  float4 c1 = c[1];  // (x2,y2,x3,y3)
  X = B0 * c0.x + B1 * c0.z + B2 * c1.x + B3 * c1.z;
  Y = B0 * c0.y + B1 * c0.w + B2 * c1.y + B3 * c1.w;
}

__device__ __forceinline__ void splat_point(float X, float Y, float* res) {
  float fx = X * (float)kW;   // bX_w - X = (w - fx)/W
  float fy = Y * (float)kW;
  int wlo = (int)ceilf(fx - kRadPix);
  int vlo = (int)ceilf(fy - kRadPix);
  float gx[kKW], gy[kKW];
  int   wi[kKW], vi[kKW];
#pragma unroll
  for (int i = 0; i < kKW; ++i) {
    int w = wlo + i;
    float dw = ((float)w - fx) * kInvW;
    bool okw = (w >= 0) && (w < kW);
    gx[i] = okw ? __expf(-dw * dw * kInvAlpha) : 0.0f;
    wi[i] = okw ? w : 0;
    int v = vlo + i;
    float dv = ((float)v - fy) * kInvW;
    bool okv = (v >= 0) && (v < kW);
    gy[i] = okv ? __expf(-dv * dv * kInvAlpha) : 0.0f;
    vi[i] = okv ? v : 0;
  }
#pragma unroll
  for (int i = 0; i < kKW; ++i) {
    int base = wi[i] * kW;     // out[b, w, v]: w (X-axis) is the row
    float g = gx[i];
#pragma unroll
    for (int j = 0; j < kKW; ++j) {
      atomicAdd(&res[base + vi[j]], g * gy[j]);
    }
  }
}

__global__ __launch_bounds__(256) void splat_kernel(const float* __restrict__ x,
                                                    float* __restrict__ acc) {
  __shared__ float res[kW * kW];
  const int b = blockIdx.x / kSplit;
  const int chunk = blockIdx.x % kSplit;
  const int tid = threadIdx.x;
  for (int i = tid; i < kW * kW; i += 256) res[i] = 0.0f;
  __syncthreads();

  const float* xb = x + (size_t)b * kL * 8;
  const int pend = (chunk + 1) * kChunk;
  for (int p = chunk * kChunk + tid; p < pend; p += 256) {
    float X, Y;
    bezier_point(xb, p, X, Y);
    splat_point(X, Y, res);
  }
  __syncthreads();

  float* accb = acc + (size_t)b * kW * kW;
  for (int i = tid; i < kW * kW; i += 256) {
    atomicAdd(&accb[i], res[i]);
  }
}

__global__ __launch_bounds__(256) void finalize_kernel(const float* __restrict__ acc,
                                                       float* __restrict__ out, int n) {
  int i = blockIdx.x * 256 + threadIdx.x;
  if (i < n) out[i] = fminf(acc[i], 1.0f);
}

// Fallback if ws is too small: one block per batch, write min() directly.
__global__ __launch_bounds__(1024) void splat_direct_kernel(const float* __restrict__ x,
                                                            float* __restrict__ out) {
  __shared__ float res[kW * kW];
  const int b = blockIdx.x;
  const int tid = threadIdx.x;
  for (int i = tid; i < kW * kW; i += 1024) res[i] = 0.0f;
  __syncthreads();

  const float* xb = x + (size_t)b * kL * 8;
  for (int p = tid; p < kPts; p += 1024) {
    float X, Y;
    bezier_point(xb, p, X, Y);
    splat_point(X, Y, res);
  }
  __syncthreads();

  float* outb = out + (size_t)b * kW * kW;
  for (int i = tid; i < kW * kW; i += 1024) {
    outb[i] = fminf(res[i], 1.0f);
  }
}

extern "C" void kernel_launch(void* const* d_in, const int* in_sizes, int n_in,
                              void* d_out, int out_size, void* d_ws, size_t ws_size,
                              hipStream_t stream) {
  const float* x = (const float*)d_in[0];
  float* out = (float*)d_out;
  const size_t acc_bytes = (size_t)kB * kW * kW * sizeof(float);

  if (ws_size >= acc_bytes) {
    float* acc = (float*)d_ws;
    hipMemsetAsync(acc, 0, acc_bytes, stream);
    splat_kernel<<<dim3(kB * kSplit), dim3(256), 0, stream>>>(x, acc);
    int n = kB * kW * kW;
    finalize_kernel<<<dim3((n + 255) / 256), dim3(256), 0, stream>>>(acc, out, n);
  } else {
    splat_direct_kernel<<<dim3(kB), dim3(1024), 0, stream>>>(x, out);
  }
}

// Round 2
// 36.136 us; speedup vs baseline: 6.1677x; 6.1677x over previous
//
#include <hip/hip_runtime.h>

// Bezier2Image via separable GEMM on matrix cores:
//   res[b,w,v] = sum_k gX[b,w,k] * gY[b,v,k],  k = (curve, sample)
// gX/gY staged truncated (8-px gaussian window) into LDS as f16,
// contracted with mfma_f32_16x16x32_f16 (fp32 accumulate).

namespace {
constexpr int   kN = 30;            // samples per curve
constexpr int   kW = 60;            // image side
constexpr int   kL = 160;           // curves per batch
constexpr int   kB = 128;           // batch
constexpr float kAlphaInv = 5000.0f;  // 1/2e-4
constexpr float kRadPix = 3.5f;     // truncation radius in pixels
constexpr int   KSPLIT = 4;         // K-split blocks per batch
constexpr int   CPB = kL / KSPLIT;  // 40 curves per block
constexpr int   KPC = 32;           // samples per curve padded to 32 (2 zero cols)
constexpr int   KBLK = CPB * KPC;   // 1280 k per block
constexpr int   KC = 128;           // k-chunk (4 curves)
constexpr int   NCH = KBLK / KC;    // 10 chunks
constexpr int   LDK = KC + 8;       // padded LDS row length (f16) -> 2-way banks only
}

using f32x4 = __attribute__((ext_vector_type(4))) float;
using f16x8 = __attribute__((ext_vector_type(8))) _Float16;

__global__ __launch_bounds__(256, 2) void bezier_gemm_kernel(const float* __restrict__ x,
                                                             float* __restrict__ acc) {
  __shared__ _Float16 sh[2][64][LDK];   // [0]=gX rows w, [1]=gY rows v ; 34.8 KB
  const int b   = blockIdx.x / KSPLIT;
  const int ks  = blockIdx.x % KSPLIT;
  const int tid = threadIdx.x;
  const int lane = tid & 63;
  const int wid  = tid >> 6;
  const int wi = wid >> 1;              // wave row-half of C
  const int vi = wid & 1;               // wave col-half of C
  const int l15 = lane & 15;
  const int l4  = lane >> 4;

  f32x4 acc4[2][2] = {};                // 2x2 tiles of 16x16, fp32

  const float* xb = x + ((size_t)b * kL + (size_t)ks * CPB) * 8;

  for (int ch = 0; ch < NCH; ++ch) {
    // ---- zero chunk ----
    uint4* shv = (uint4*)&sh[0][0][0];
    constexpr int NZ = 2 * 64 * LDK * 2 / 16;   // 2176 uint4
    for (int i = tid; i < NZ; i += 256) shv[i] = make_uint4(0, 0, 0, 0);
    __syncthreads();

    // ---- scatter truncated gaussian windows ----
    {
      const int col = tid & 127;        // k-column within chunk
      const int mat = tid >> 7;         // 0 = gX, 1 = gY
      const int kg  = ch * KC + col;    // k within block
      const int n   = kg & (KPC - 1);   // sample index (30,31 = zero pad)
      if (n < kN) {
        const int lc = kg >> 5;         // curve within block
        float t0 = (float)n * (1.0f / 30.0f);
        float t  = 2.0f * t0 * t0 * t0 - 3.0f * t0 * t0 + 2.0f * t0;
        float t2 = t * t, t3 = t2 * t;
        float B0 = t3;
        float B1 = 3.0f * (t2 - t3);
        float B2 = 3.0f * (t3 - 2.0f * t2 + t);
        float omt = 1.0f - t;
        float B3 = omt * omt * omt;
        const float4* c = (const float4*)(xb + lc * 8);
        float4 c0 = c[0], c1 = c[1];
        float P = mat ? (B0 * c0.y + B1 * c0.w + B2 * c1.y + B3 * c1.w)
                      : (B0 * c0.x + B1 * c0.z + B2 * c1.x + B3 * c1.z);
        float fp = P * (float)kW;
        int lo = (int)ceilf(fp - kRadPix);
#pragma unroll
        for (int i = 0; i < 8; ++i) {
          int m = lo + i;
          float d = (float)m * (1.0f / 60.0f) - P;
          float e = __expf(-d * d * kAlphaInv);
          if (m >= 0 && m < kW) sh[mat][m][col] = (_Float16)e;
        }
      }
    }
    __syncthreads();

    // ---- MFMA over chunk: wave (wi,vi) owns C[wi*32..+32][vi*32..+32] ----
#pragma unroll
    for (int kk = 0; kk < KC; kk += 32) {
      const int ke = kk + l4 * 8;
      f16x8 a0 = *(const f16x8*)&sh[0][wi * 32 + l15][ke];
      f16x8 a1 = *(const f16x8*)&sh[0][wi * 32 + 16 + l15][ke];
      f16x8 b0 = *(const f16x8*)&sh[1][vi * 32 + l15][ke];
      f16x8 b1 = *(const f16x8*)&sh[1][vi * 32 + 16 + l15][ke];
      acc4[0][0] = __builtin_amdgcn_mfma_f32_16x16x32_f16(a0, b0, acc4[0][0], 0, 0, 0);
      acc4[0][1] = __builtin_amdgcn_mfma_f32_16x16x32_f16(a0, b1, acc4[0][1], 0, 0, 0);
      acc4[1][0] = __builtin_amdgcn_mfma_f32_16x16x32_f16(a1, b0, acc4[1][0], 0, 0, 0);
      acc4[1][1] = __builtin_amdgcn_mfma_f32_16x16x32_f16(a1, b1, acc4[1][1], 0, 0, 0);
    }
    __syncthreads();
  }

  // ---- store partial C: D layout col=lane&15, row=(lane>>4)*4+r ----
  float* ab = acc + (size_t)b * kW * kW;
#pragma unroll
  for (int mt = 0; mt < 2; ++mt) {
#pragma unroll
    for (int vt = 0; vt < 2; ++vt) {
      const int v = vi * 32 + vt * 16 + l15;
#pragma unroll
      for (int r = 0; r < 4; ++r) {
        const int w = wi * 32 + mt * 16 + l4 * 4 + r;
        if (w < kW && v < kW) atomicAdd(&ab[w * kW + v], acc4[mt][vt][r]);
      }
    }
  }
}

__global__ __launch_bounds__(256) void finalize_kernel(const float* __restrict__ acc,
                                                       float* __restrict__ out, int n) {
  int i = blockIdx.x * 256 + threadIdx.x;
  if (i < n) out[i] = fminf(acc[i], 1.0f);
}

// Fallback if ws is too small: one block per batch, LDS-atomic splat, direct write.
__global__ __launch_bounds__(1024) void splat_direct_kernel(const float* __restrict__ x,
                                                            float* __restrict__ out) {
  __shared__ float res[kW * kW];
  const int b = blockIdx.x;
  const int tid = threadIdx.x;
  for (int i = tid; i < kW * kW; i += 1024) res[i] = 0.0f;
  __syncthreads();
  const float* xb = x + (size_t)b * kL * 8;
  for (int p = tid; p < kL * kN; p += 1024) {
    int l = p / kN;
    int n = p - l * kN;
    float t0 = (float)n * (1.0f / 30.0f);
    float t  = 2.0f * t0 * t0 * t0 - 3.0f * t0 * t0 + 2.0f * t0;
    float t2 = t * t, t3 = t2 * t;
    float B0 = t3, B1 = 3.0f * (t2 - t3), B2 = 3.0f * (t3 - 2.0f * t2 + t);
    float omt = 1.0f - t, B3 = omt * omt * omt;
    const float4* c = (const float4*)(xb + l * 8);
    float4 c0 = c[0], c1 = c[1];
    float X = B0 * c0.x + B1 * c0.z + B2 * c1.x + B3 * c1.z;
    float Y = B0 * c0.y + B1 * c0.w + B2 * c1.y + B3 * c1.w;
    float fx = X * kW, fy = Y * kW;
    int wlo = (int)ceilf(fx - kRadPix), vlo = (int)ceilf(fy - kRadPix);
    for (int i = 0; i < 8; ++i) {
      int w = wlo + i;
      if (w < 0 || w >= kW) continue;
      float dw = ((float)w - fx) * (1.0f / kW);
      float gx = __expf(-dw * dw * kAlphaInv);
      for (int j = 0; j < 8; ++j) {
        int v = vlo + j;
        if (v < 0 || v >= kW) continue;
        float dv = ((float)v - fy) * (1.0f / kW);
        atomicAdd(&res[w * kW + v], gx * __expf(-dv * dv * kAlphaInv));
      }
    }
  }
  __syncthreads();
  float* outb = out + (size_t)b * kW * kW;
  for (int i = tid; i < kW * kW; i += 1024) outb[i] = fminf(res[i], 1.0f);
}

extern "C" void kernel_launch(void* const* d_in, const int* in_sizes, int n_in,
                              void* d_out, int out_size, void* d_ws, size_t ws_size,
                              hipStream_t stream) {
  const float* x = (const float*)d_in[0];
  float* out = (float*)d_out;
  const size_t acc_bytes = (size_t)kB * kW * kW * sizeof(float);

  if (ws_size >= acc_bytes) {
    float* acc = (float*)d_ws;
    hipMemsetAsync(acc, 0, acc_bytes, stream);
    bezier_gemm_kernel<<<dim3(kB * KSPLIT), dim3(256), 0, stream>>>(x, acc);
    int n = kB * kW * kW;
    finalize_kernel<<<dim3((n + 255) / 256), dim3(256), 0, stream>>>(acc, out, n);
  } else {
    splat_direct_kernel<<<dim3(kB), dim3(1024), 0, stream>>>(x, out);
  }
}

// Round 3
// 23.967 us; speedup vs baseline: 9.2993x; 1.5078x over previous
//
#include <hip/hip_runtime.h>

// Bezier2Image via separable GEMM on matrix cores:
//   res[b,w,v] = sum_k gX[b,w,k] * gY[b,v,k],  k = (curve, sample)
// gX/gY staged truncated (8-px gaussian window) into LDS as f16,
// contracted with mfma_f32_16x16x32_f16 (fp32 accumulate).
// Split-K partials are plain-stored to ws (no atomics, no memset),
// then reduced + clamped by a second kernel.

namespace {
constexpr int   kN = 30;            // samples per curve
constexpr int   kW = 60;            // image side
constexpr int   kL = 160;           // curves per batch
constexpr int   kB = 128;           // batch
constexpr float kAlphaInv = 5000.0f;  // 1/2e-4
constexpr float kRadPix = 3.5f;     // truncation radius in pixels
constexpr int   KSPLIT = 4;         // K-split blocks per batch
constexpr int   CPB = kL / KSPLIT;  // 40 curves per block
constexpr int   KPC = 32;           // samples per curve padded to 32
constexpr int   KBLK = CPB * KPC;   // 1280 k per block
constexpr int   KC = 128;           // k-chunk (4 curves)
constexpr int   NCH = KBLK / KC;    // 10 chunks
constexpr int   LDK = KC + 8;       // padded LDS row length (f16)
constexpr int   kPix = kW * kW;     // 3600
}

using f32x4 = __attribute__((ext_vector_type(4))) float;
using f16x8 = __attribute__((ext_vector_type(8))) _Float16;

__global__ __launch_bounds__(256, 2) void bezier_gemm_kernel(const float* __restrict__ x,
                                                             float* __restrict__ partial) {
  __shared__ _Float16 sh[2][64][LDK];   // [0]=gX rows w, [1]=gY rows v ; 34.8 KB
  const int b   = blockIdx.x / KSPLIT;
  const int ks  = blockIdx.x % KSPLIT;
  const int tid = threadIdx.x;
  const int lane = tid & 63;
  const int wid  = tid >> 6;
  const int wi = wid >> 1;              // wave row-half of C
  const int vi = wid & 1;               // wave col-half of C
  const int l15 = lane & 15;
  const int l4  = lane >> 4;

  f32x4 acc4[2][2] = {};                // 2x2 tiles of 16x16, fp32

  const float* xb = x + ((size_t)b * kL + (size_t)ks * CPB) * 8;

  // ---- initial full zero of the staging tile (covers pads + rows>=60) ----
  {
    uint4* shv = (uint4*)&sh[0][0][0];
    constexpr int NZ = 2 * 64 * LDK * 2 / 16;
    for (int i = tid; i < NZ; i += 256) shv[i] = make_uint4(0, 0, 0, 0);
  }

  // ---- per-thread fixed staging role: one (matrix, column) ----
  const int col = tid & 127;            // k-column within chunk (constant)
  const int mat = tid >> 7;             // 0 = gX, 1 = gY       (constant)
  const int n   = col & (KPC - 1);      // sample index (constant; 30,31 = pad)
  const bool valid = (n < kN);
  // Bernstein basis: constant per thread, hoisted out of the chunk loop
  float B0, B1, B2, B3;
  {
    float t0 = (float)n * (1.0f / 30.0f);
    float t  = 2.0f * t0 * t0 * t0 - 3.0f * t0 * t0 + 2.0f * t0;
    float t2 = t * t, t3 = t2 * t;
    B0 = t3;
    B1 = 3.0f * (t2 - t3);
    B2 = 3.0f * (t3 - 2.0f * t2 + t);
    float omt = 1.0f - t;
    B3 = omt * omt * omt;
  }
  int lo_prev = 0;                      // rows 0..7 are zero; re-zeroing is harmless

  __syncthreads();                      // initial zero visible to all

  for (int ch = 0; ch < NCH; ++ch) {
    // ---- scatter: zero own old window, write own new window (column-exclusive) ----
    if (valid) {
      const int lc = ch * 4 + (col >> 5);   // curve within block
      const float4* c = (const float4*)(xb + lc * 8);
      float4 c0 = c[0], c1 = c[1];
      float P = mat ? (B0 * c0.y + B1 * c0.w + B2 * c1.y + B3 * c1.w)
                    : (B0 * c0.x + B1 * c0.z + B2 * c1.x + B3 * c1.z);
      float fp = P * (float)kW;
      int lo = (int)ceilf(fp - kRadPix);
#pragma unroll
      for (int i = 0; i < 8; ++i) {
        int m = lo_prev + i;
        if (m >= 0 && m < kW) sh[mat][m][col] = (_Float16)0.0f;
      }
#pragma unroll
      for (int i = 0; i < 8; ++i) {
        int m = lo + i;
        float d = (float)m * (1.0f / 60.0f) - P;
        float e = __expf(-d * d * kAlphaInv);
        if (m >= 0 && m < kW) sh[mat][m][col] = (_Float16)e;
      }
      lo_prev = lo;
    }
    __syncthreads();

    // ---- MFMA over chunk: wave (wi,vi) owns C[wi*32..+32][vi*32..+32] ----
#pragma unroll
    for (int kk = 0; kk < KC; kk += 32) {
      const int ke = kk + l4 * 8;
      f16x8 a0 = *(const f16x8*)&sh[0][wi * 32 + l15][ke];
      f16x8 a1 = *(const f16x8*)&sh[0][wi * 32 + 16 + l15][ke];
      f16x8 b0 = *(const f16x8*)&sh[1][vi * 32 + l15][ke];
      f16x8 b1 = *(const f16x8*)&sh[1][vi * 32 + 16 + l15][ke];
      acc4[0][0] = __builtin_amdgcn_mfma_f32_16x16x32_f16(a0, b0, acc4[0][0], 0, 0, 0);
      acc4[0][1] = __builtin_amdgcn_mfma_f32_16x16x32_f16(a0, b1, acc4[0][1], 0, 0, 0);
      acc4[1][0] = __builtin_amdgcn_mfma_f32_16x16x32_f16(a1, b0, acc4[1][0], 0, 0, 0);
      acc4[1][1] = __builtin_amdgcn_mfma_f32_16x16x32_f16(a1, b1, acc4[1][1], 0, 0, 0);
    }
    __syncthreads();   // MFMA reads done before next chunk's scatter overwrites
  }

  // ---- plain-store partial C: D layout col=lane&15, row=(lane>>4)*4+r ----
  float* pb = partial + (size_t)blockIdx.x * kPix;
#pragma unroll
  for (int mt = 0; mt < 2; ++mt) {
#pragma unroll
    for (int vt = 0; vt < 2; ++vt) {
      const int v = vi * 32 + vt * 16 + l15;
#pragma unroll
      for (int r = 0; r < 4; ++r) {
        const int w = wi * 32 + mt * 16 + l4 * 4 + r;
        if (w < kW && v < kW) pb[w * kW + v] = acc4[mt][vt][r];
      }
    }
  }
}

__global__ __launch_bounds__(256) void reduce_kernel(const float* __restrict__ partial,
                                                     float* __restrict__ out) {
  int i = blockIdx.x * 256 + threadIdx.x;
  if (i >= kB * kPix) return;
  int b = i / kPix;
  int j = i - b * kPix;
  const float* p = partial + (size_t)b * KSPLIT * kPix + j;
  float s = p[0] + p[kPix] + p[2 * kPix] + p[3 * kPix];
  out[i] = fminf(s, 1.0f);
}

// Fallback if ws is too small: one block per batch, LDS-atomic splat, direct write.
__global__ __launch_bounds__(1024) void splat_direct_kernel(const float* __restrict__ x,
                                                            float* __restrict__ out) {
  __shared__ float res[kPix];
  const int b = blockIdx.x;
  const int tid = threadIdx.x;
  for (int i = tid; i < kPix; i += 1024) res[i] = 0.0f;
  __syncthreads();
  const float* xb = x + (size_t)b * kL * 8;
  for (int p = tid; p < kL * kN; p += 1024) {
    int l = p / kN;
    int n = p - l * kN;
    float t0 = (float)n * (1.0f / 30.0f);
    float t  = 2.0f * t0 * t0 * t0 - 3.0f * t0 * t0 + 2.0f * t0;
    float t2 = t * t, t3 = t2 * t;
    float B0 = t3, B1 = 3.0f * (t2 - t3), B2 = 3.0f * (t3 - 2.0f * t2 + t);
    float omt = 1.0f - t, B3 = omt * omt * omt;
    const float4* c = (const float4*)(xb + l * 8);
    float4 c0 = c[0], c1 = c[1];
    float X = B0 * c0.x + B1 * c0.z + B2 * c1.x + B3 * c1.z;
    float Y = B0 * c0.y + B1 * c0.w + B2 * c1.y + B3 * c1.w;
    float fx = X * kW, fy = Y * kW;
    int wlo = (int)ceilf(fx - kRadPix), vlo = (int)ceilf(fy - kRadPix);
    for (int i = 0; i < 8; ++i) {
      int w = wlo + i;
      if (w < 0 || w >= kW) continue;
      float dw = ((float)w - fx) * (1.0f / kW);
      float gx = __expf(-dw * dw * kAlphaInv);
      for (int j = 0; j < 8; ++j) {
        int v = vlo + j;
        if (v < 0 || v >= kW) continue;
        float dv = ((float)v - fy) * (1.0f / kW);
        atomicAdd(&res[w * kW + v], gx * __expf(-dv * dv * kAlphaInv));
      }
    }
  }
  __syncthreads();
  float* outb = out + (size_t)b * kPix;
  for (int i = tid; i < kPix; i += 1024) outb[i] = fminf(res[i], 1.0f);
}

extern "C" void kernel_launch(void* const* d_in, const int* in_sizes, int n_in,
                              void* d_out, int out_size, void* d_ws, size_t ws_size,
                              hipStream_t stream) {
  const float* x = (const float*)d_in[0];
  float* out = (float*)d_out;
  const size_t part_bytes = (size_t)kB * KSPLIT * kPix * sizeof(float);

  if (ws_size >= part_bytes) {
    float* partial = (float*)d_ws;
    bezier_gemm_kernel<<<dim3(kB * KSPLIT), dim3(256), 0, stream>>>(x, partial);
    int n = kB * kPix;
    reduce_kernel<<<dim3((n + 255) / 256), dim3(256), 0, stream>>>(partial, out);
  } else {
    splat_direct_kernel<<<dim3(kB), dim3(1024), 0, stream>>>(x, out);
  }
}